// Round 12
// baseline (723.930 us; speedup 1.0000x reference)
//
#include <hip/hip_runtime.h>
#include <hip/hip_bf16.h>

// Problem constants (from reference)
#define NN 16384
#define EE 65536
#define DD 64
#define HH 128
#define LL 3
#define GG 512
#define OUTD 128
#define NEG 0.01f   // jax.nn.leaky_relu default slope

#define CHUNK 4096   // nodes per S chunk (S chunk = 4096 x 8192 bf16 = 64 MiB, ping-pong x2)
#define KSEG 8       // split-K partial buffers
#define SBB (CHUNK/2)          // sbuild blocks per chunk (2 nodes/block)
#define GMB ((CHUNK/128)*KSEG) // gemm blocks per chunk = 32*8 = 256

// S column permutation (v4, d-split writer-natural order):
// c' bits: [12]=q, [11:9]=i, [8:3]=lane, [2:1]=j, [0]=kk
// -> u-index idx = 2*lane + kk ; d = 32*q + 4*i + j ; legacy kd = idx*64 + d.
// W2T' bakes the same permutation; gemm dots over c' linearly (layout-agnostic).

typedef __attribute__((ext_vector_type(8))) short short8;
typedef __attribute__((ext_vector_type(4))) float f32x4;

__device__ __forceinline__ float leaky(float x){ return x > 0.f ? x : NEG * x; }
__device__ __forceinline__ unsigned short f2bf(float f){
  union { float f; unsigned int u; } v; v.f = f;
  unsigned int r = v.u + 0x7fffu + ((v.u >> 16) & 1u);   // RNE
  return (unsigned short)(r >> 16);
}

#define CV_A (EE*DD)            // 4194304
#define CV_B (LL*HH*DD)         // 24576
#define CV_C (LL*64*8192)       // 1572864
#define PRE0 (NN/4)             // init_ln blocks
#define PRE1 ((CV_A+CV_B+CV_C)/256)
#define PRE2 (EE/256)

// ---------------- merged pre-kernel: init+LN0 | bf16 conversions | deg/cnt ----------------
__global__ void k_pre(const float* x_in, const float* ln_s, const float* ln_b,
                      float* x_cur, float* h, int* deg, int* cursor, int* cnt, float* pooled,
                      const float* ea, const float* W1, const float* W2,
                      unsigned short* eab, unsigned short* W1T, unsigned short* W2T,
                      const int* ei, const int* batch){
  int t = threadIdx.x;
  int b = blockIdx.x;
  if (b < PRE0){
    int i = b*256 + t;
    if (i < NN){ deg[i] = 0; cursor[i] = 0; }
    if (i < GG) cnt[i] = 0;
    if (i < GG*DD) pooled[i] = 0.f;
    int lane = t & 63, nl = t >> 6;
    int n = b*4 + nl;
    float v = x_in[(size_t)n*DD + lane];
    x_cur[(size_t)n*DD + lane] = v;
    float s = v;
    for (int m=1;m<64;m<<=1) s += __shfl_xor(s, m, 64);
    float mu = s * (1.0f/64.0f);
    float dv = v - mu;
    float q = dv*dv;
    for (int m=1;m<64;m<<=1) q += __shfl_xor(q, m, 64);
    float var = q * (1.0f/64.0f);
    float w = dv * rsqrtf(var + 1e-5f) * ln_s[lane] + ln_b[lane];
    h[(size_t)n*DD + lane] = leaky(w);
    return;
  }
  if (b < PRE0 + PRE1){
    int idx = (b - PRE0)*256 + t;
    if (idx < CV_A){
      eab[idx] = f2bf(ea[idx]);
    } else if (idx < CV_A + CV_B){
      int i = idx - CV_A;
      int l = i >> 13, r = i & 8191;
      int j = r >> 6, d = r & 63;
      W1T[i] = f2bf(W1[(size_t)l*DD*HH + d*HH + j]);   // W1T[l][j][d]
    } else {
      int i = idx - CV_A - CV_B;
      int l = i >> 19, rem = i & ((1<<19)-1);          // 64*8192 per layer
      int f = rem >> 13, c = rem & 8191;
      // v4 permutation decode
      int kk = c & 1, j = (c>>1) & 3, lane = (c>>3) & 63, ii = (c>>9) & 7, q = (c>>12) & 1;
      int idxu = 2*lane + kk;
      int d = 32*q + 4*ii + j;
      int kd = idxu*64 + d;
      W2T[i] = f2bf(W2[(size_t)l*HH*DD*DD + (size_t)kd*DD + f]);
    }
    return;
  }
  {
    int e = (b - PRE0 - PRE1)*256 + t;
    atomicAdd(&deg[ei[EE + e]], 1);          // row 1 of edge_index = dst
    if (e < NN) atomicAdd(&cnt[batch[e]], 1);
  }
}

__global__ void k_scan(const int* deg, int* row_ptr){
  __shared__ int part[256];
  int t = threadIdx.x;
  int base = t*64; int s = 0;
  for (int i=0;i<64;++i) s += deg[base+i];
  part[t] = s; __syncthreads();
  for (int off=1; off<256; off<<=1){
    int v = (t>=off)?part[t-off]:0; __syncthreads();
    part[t] += v; __syncthreads();
  }
  int run = (t==0)?0:part[t-1];
  if (t==0) row_ptr[0] = 0;
  for (int i=0;i<64;++i){ run += deg[base+i]; row_ptr[base+i+1] = run; }
}
__global__ void k_fill(const int* ei, const int* row_ptr, int* cursor,
                       int* edge_id, int* src_sorted){
  int e = blockIdx.x*256 + threadIdx.x;
  if (e < EE){
    int d = ei[EE + e];
    int pos = row_ptr[d] + atomicAdd(&cursor[d], 1);
    edge_id[pos] = e;
    src_sorted[pos] = ei[e];      // row 0 of edge_index = src
  }
}

// ---------------- edge MLP (ALL 3 layers up front): ug[l] = bf16(leaky(ea@W1[l]+b1[l])) ------
__global__ __launch_bounds__(256, 2)
void k_mlp3(const unsigned short* eab, const unsigned short* W1T, const float* b1,
            unsigned short* ug){
  __shared__ __align__(16) unsigned short a_lds[128][72];   // ea tile  [e][d]
  __shared__ __align__(16) unsigned short b_lds[128][72];   // W1T      [j][d]
  __shared__ __align__(16) unsigned short c_lds[128][136];  // out      [e][j]
  int t = threadIdx.x;
  int l  = blockIdx.x >> 9;                 // EE/128 = 512 blocks per layer
  int e0 = (blockIdx.x & 511) * 128;
  {
    int row = t >> 1, col = (t & 1) * 32;
    const float4* sa = (const float4*)(eab + (size_t)(e0 + row)*DD + col);
    const float4* sb = (const float4*)(W1T + (size_t)l*HH*DD + (size_t)row*DD + col);
    #pragma unroll
    for (int i=0;i<4;++i){
      *(float4*)&a_lds[row][col + 8*i] = sa[i];
      *(float4*)&b_lds[row][col + 8*i] = sb[i];
    }
  }
  __syncthreads();
  int wave = t >> 6, lane = t & 63;
  int m0 = (wave >> 1) * 64, j0 = (wave & 1) * 64;
  int lr = lane & 15, lq = lane >> 4;
  f32x4 acc[4][4];
  #pragma unroll
  for (int a=0;a<4;++a)
    #pragma unroll
    for (int b=0;b<4;++b) acc[a][b] = (f32x4){0.f,0.f,0.f,0.f};
  #pragma unroll
  for (int ks=0; ks<2; ++ks){
    short8 av[4];
    #pragma unroll
    for (int mt=0; mt<4; ++mt) av[mt] = *(const short8*)&a_lds[m0 + mt*16 + lr][ks*32 + lq*8];
    #pragma unroll
    for (int jt=0; jt<4; ++jt){
      short8 bv = *(const short8*)&b_lds[j0 + jt*16 + lr][ks*32 + lq*8];
      #pragma unroll
      for (int mt=0; mt<4; ++mt)
        acc[mt][jt] = __builtin_amdgcn_mfma_f32_16x16x32_bf16(av[mt], bv, acc[mt][jt], 0, 0, 0);
    }
  }
  // C/D: col = lane&15, row = (lane>>4)*4 + r
  #pragma unroll
  for (int mt=0; mt<4; ++mt)
    #pragma unroll
    for (int jt=0; jt<4; ++jt){
      int col = j0 + jt*16 + lr;
      float bj = b1[l*HH + col];
      #pragma unroll
      for (int r=0; r<4; ++r){
        int row = m0 + mt*16 + lq*4 + r;
        c_lds[row][col] = f2bf(leaky(acc[mt][jt][r] + bj));
      }
    }
  __syncthreads();
  {
    int row = t >> 1, half = t & 1;
    float4* dst = (float4*)(ug + (size_t)l*EE*HH + (size_t)(e0 + row)*HH + half*64);
    #pragma unroll
    for (int i=0;i<8;++i) dst[i] = *(const float4*)&c_lds[row][half*64 + 8*i];
  }
}

// ---------------- merged sbuild(chunk i) + gemm(chunk i-1): role by blockIdx ----------------
// sbuild v4: d-split, 2 waves/node; gemm: M=128, BK=64, direct num_part stores.
// gemm reads S written by the PREVIOUS launch -> no intra-launch ordering assumed.
__global__ __launch_bounds__(256, 2)
void k_sbgm(const unsigned short* ug, const float* h, const int* row_ptr,
            const int* edge_id, const int* src_sorted,
            unsigned short* S_w, float* Hs, int sb_base, int sb_blocks,
            const unsigned short* S_r, const unsigned short* W2T,
            float* num_part, int gm_base){
  __shared__ __align__(16) unsigned short a_lds[128][72];
  __shared__ __align__(16) unsigned short b_lds[64][72];
  int t = threadIdx.x, wave = t >> 6, lane = t & 63;
  if ((int)blockIdx.x < sb_blocks){
    // ================= sbuild role =================
    int q = wave & 1;
    int nloc = blockIdx.x*2 + (wave >> 1);
    int n = sb_base + nloc;
    int r0 = row_ptr[n], r1 = row_ptr[n+1];
    int dbase = 32*q;
    int lhalf = lane & 31;
    const unsigned int* ugd = (const unsigned int*)ug;
    float acc[64];                            // acc[dd*2+kk]
    #pragma unroll
    for (int i=0;i<64;++i) acc[i] = 0.f;
    float hs = 0.f;
    int pos = r0;
    for (; pos + 4 <= r1; pos += 4){          // two (a,b) pairs per iter
      int ea0 = edge_id[pos],    eb0 = edge_id[pos+1];
      int ea1 = edge_id[pos+2],  eb1 = edge_id[pos+3];
      int sa0 = src_sorted[pos],   sb0 = src_sorted[pos+1];
      int sa1 = src_sorted[pos+2], sb1 = src_sorted[pos+3];
      int sel0 = (lane < 32) ? sa0 : sb0;
      int sel1 = (lane < 32) ? sa1 : sb1;
      float hv0 = h[(size_t)sel0*DD + dbase + lhalf];
      float hv1 = h[(size_t)sel1*DD + dbase + lhalf];
      unsigned int ua0 = ugd[(size_t)ea0*64 + lane];
      unsigned int ub0 = ugd[(size_t)eb0*64 + lane];
      unsigned int ua1 = ugd[(size_t)ea1*64 + lane];
      unsigned int ub1 = ugd[(size_t)eb1*64 + lane];
      hs += hv0 + hv1;
      int h0 = __float_as_int(hv0), h1 = __float_as_int(hv1);
      float ua0l = __uint_as_float(ua0 << 16), ua0h = __uint_as_float(ua0 & 0xFFFF0000u);
      float ub0l = __uint_as_float(ub0 << 16), ub0h = __uint_as_float(ub0 & 0xFFFF0000u);
      float ua1l = __uint_as_float(ua1 << 16), ua1h = __uint_as_float(ua1 & 0xFFFF0000u);
      float ub1l = __uint_as_float(ub1 << 16), ub1h = __uint_as_float(ub1 & 0xFFFF0000u);
      #pragma unroll
      for (int dd=0; dd<32; ++dd){
        float sa_ = __int_as_float(__builtin_amdgcn_readlane(h0, dd));
        float sb_ = __int_as_float(__builtin_amdgcn_readlane(h0, 32+dd));
        float sa2 = __int_as_float(__builtin_amdgcn_readlane(h1, dd));
        float sb2 = __int_as_float(__builtin_amdgcn_readlane(h1, 32+dd));
        acc[dd*2+0] += ua0l*sa_; acc[dd*2+1] += ua0h*sa_;
        acc[dd*2+0] += ub0l*sb_; acc[dd*2+1] += ub0h*sb_;
        acc[dd*2+0] += ua1l*sa2; acc[dd*2+1] += ua1h*sa2;
        acc[dd*2+0] += ub1l*sb2; acc[dd*2+1] += ub1h*sb2;
      }
    }
    for (; pos + 2 <= r1; pos += 2){          // one (a,b) pair
      int ea = edge_id[pos],  eb = edge_id[pos+1];
      int sa = src_sorted[pos], sb = src_sorted[pos+1];
      int sel = (lane < 32) ? sa : sb;
      float hv = h[(size_t)sel*DD + dbase + lhalf];
      unsigned int ua = ugd[(size_t)ea*64 + lane];
      unsigned int ub = ugd[(size_t)eb*64 + lane];
      hs += hv;
      int h0 = __float_as_int(hv);
      float ual = __uint_as_float(ua << 16), uah = __uint_as_float(ua & 0xFFFF0000u);
      float ubl = __uint_as_float(ub << 16), ubh = __uint_as_float(ub & 0xFFFF0000u);
      #pragma unroll
      for (int dd=0; dd<32; ++dd){
        float sa_ = __int_as_float(__builtin_amdgcn_readlane(h0, dd));
        float sb_ = __int_as_float(__builtin_amdgcn_readlane(h0, 32+dd));
        acc[dd*2+0] += ual*sa_; acc[dd*2+1] += uah*sa_;
        acc[dd*2+0] += ubl*sb_; acc[dd*2+1] += ubh*sb_;
      }
    }
    if (pos < r1){                            // single remainder edge
      int e = edge_id[pos], s = src_sorted[pos];
      float hv = h[(size_t)s*DD + dbase + lhalf];
      unsigned int ua = ugd[(size_t)e*64 + lane];
      hs += (lane < 32) ? hv : 0.f;
      int h0 = __float_as_int(hv);
      float ual = __uint_as_float(ua << 16), uah = __uint_as_float(ua & 0xFFFF0000u);
      #pragma unroll
      for (int dd=0; dd<32; ++dd){
        float sa_ = __int_as_float(__builtin_amdgcn_readlane(h0, dd));
        acc[dd*2+0] += ual*sa_; acc[dd*2+1] += uah*sa_;
      }
    }
    float4* Srow4 = (float4*)(S_w + (size_t)nloc*8192);
    #pragma unroll
    for (int i=0;i<8;++i){
      union { unsigned int u[4]; float4 v; } b;
      #pragma unroll
      for (int j=0;j<4;++j){
        int dd = 4*i + j;
        b.u[j] = (unsigned int)f2bf(acc[dd*2+0]) | ((unsigned int)f2bf(acc[dd*2+1]) << 16);
      }
      Srow4[(q*8 + i)*64 + lane] = b.v;
    }
    float hs2 = hs + __shfl_xor(hs, 32, 64);
    if (lane < 32) Hs[(size_t)n*DD + dbase + lane] = hs2;
    return;
  }
  // ================= gemm role =================
  {
    int g = blockIdx.x - sb_blocks;
    int kseg = g & 7, rowblk = g >> 3;
    int lr = lane & 15, lq = lane >> 4;
    f32x4 acc[2][4];
    #pragma unroll
    for (int a=0;a<2;++a)
      #pragma unroll
      for (int b=0;b<4;++b) acc[a][b] = (f32x4){0.f,0.f,0.f,0.f};
    int m0 = wave * 32;
    for (int it = 0; it < 16; ++it){          // 16 x 64 = 1024 kd per kseg
      int kbase = kseg*1024 + it*64;
      #pragma unroll
      for (int ii=0; ii<4; ++ii){             // stage A: 128 rows x 64 kd
        int idx = t + 256*ii;
        int r = idx >> 3, c8 = (idx & 7) << 3;
        *(float4*)&a_lds[r][c8] =
          *(const float4*)(S_r + (size_t)(rowblk*128 + r)*8192 + kbase + c8);
      }
      #pragma unroll
      for (int ii=0; ii<2; ++ii){             // stage B: 64 f x 64 kd
        int idx = t + 256*ii;
        int r = idx >> 3, c8 = (idx & 7) << 3;
        *(float4*)&b_lds[r][c8] =
          *(const float4*)(W2T + (size_t)r*8192 + kbase + c8);
      }
      __syncthreads();
      #pragma unroll
      for (int kk=0; kk<64; kk+=32){
        short8 a0 = *(const short8*)&a_lds[m0 + lr][kk + lq*8];
        short8 a1 = *(const short8*)&a_lds[m0 + 16 + lr][kk + lq*8];
        #pragma unroll
        for (int ft=0; ft<4; ++ft){
          short8 bv = *(const short8*)&b_lds[ft*16 + lr][kk + lq*8];
          acc[0][ft] = __builtin_amdgcn_mfma_f32_16x16x32_bf16(a0, bv, acc[0][ft], 0, 0, 0);
          acc[1][ft] = __builtin_amdgcn_mfma_f32_16x16x32_bf16(a1, bv, acc[1][ft], 0, 0, 0);
        }
      }
      __syncthreads();
    }
    // C/D layout: col = lane&15, row = (lane>>4)*4 + reg
    float* dstp = num_part + (size_t)kseg*NN*DD;
    #pragma unroll
    for (int rt=0; rt<2; ++rt)
      #pragma unroll
      for (int ft=0; ft<4; ++ft)
        #pragma unroll
        for (int rr=0; rr<4; ++rr){
          int m = m0 + rt*16 + lq*4 + rr;
          int f = ft*16 + lr;
          int n = gm_base + rowblk*128 + m;
          dstp[(size_t)n*DD + f] = acc[rt][ft][rr];
        }
  }
}

// ---------------- node update (+ fused next-layer LN, + fused head dense+pool) ---------------
__global__ void k_update_ln(float* x, const float* num_part, float* h, const float* Hs,
                            const int* deg, const float* root, const float* b2,
                            const float* conv_b, const float* ln_s, const float* ln_b,
                            const float* dW, const float* db, const int* batch, float* pooled,
                            int l, int do_ln, int do_head){
  __shared__ float rl[64][64];
  __shared__ float b2l[64][64];
  __shared__ float wl[64][64];
  __shared__ float hrow[4][64];
  __shared__ float hsrow[4][64];
  __shared__ float xrow[4][64];
  int t = threadIdx.x;
  int f = t & 63, nl = t >> 6;
  for (int idx=t; idx<4096; idx+=256){
    rl[idx>>6][idx&63]  = root[(size_t)l*4096 + idx];
    b2l[idx>>6][idx&63] = b2[(size_t)l*4096 + idx];
    if (do_head) wl[idx>>6][idx&63] = dW[idx];
  }
  int n = blockIdx.x*4 + nl;
  hrow[nl][f]  = h[(size_t)n*DD + f];
  hsrow[nl][f] = Hs[(size_t)n*DD + f];
  __syncthreads();
  float dg = (float)deg[n]; if (dg < 1.f) dg = 1.f;
  float nsum = 0.f;
  #pragma unroll
  for (int p=0; p<KSEG; ++p) nsum += num_part[(size_t)p*NN*DD + (size_t)n*DD + f];
  float acc = x[(size_t)n*DD + f] + nsum/dg + conv_b[l*DD + f];
  #pragma unroll
  for (int d=0; d<64; ++d)
    acc += hrow[nl][d]*rl[d][f] + hsrow[nl][d]*b2l[d][f];
  x[(size_t)n*DD + f] = acc;
  if (do_ln){
    int lp = l + 1;
    float s = acc;
    for (int m=1;m<64;m<<=1) s += __shfl_xor(s, m, 64);
    float mu = s * (1.0f/64.0f);
    float dv = acc - mu;
    float qv = dv*dv;
    for (int m=1;m<64;m<<=1) qv += __shfl_xor(qv, m, 64);
    float var = qv * (1.0f/64.0f);
    float w = dv * rsqrtf(var + 1e-5f) * ln_s[lp*DD + f] + ln_b[lp*DD + f];
    h[(size_t)n*DD + f] = leaky(w);
  }
  if (do_head){
    xrow[nl][f] = acc;
    __syncthreads();
    float hacc = db[f];
    #pragma unroll
    for (int d=0; d<64; ++d) hacc += xrow[nl][d]*wl[d][f];
    atomicAdd(&pooled[(size_t)batch[n]*DD + f], hacc);
  }
}

__global__ void k_final(const float* pooled, const int* cnt, const float* oW,
                        const float* ob, float* out){
  __shared__ float p[64];
  int g = blockIdx.x, t = threadIdx.x;
  if (t < 64){
    float c = (float)cnt[g]; if (c < 1.f) c = 1.f;
    p[t] = leaky(pooled[(size_t)g*DD + t] / c);
  }
  __syncthreads();
  float acc = ob[t];
  #pragma unroll
  for (int f=0; f<64; ++f) acc += p[f]*oW[(size_t)f*OUTD + t];
  out[(size_t)g*OUTD + t] = acc;
}

// ws too small -> emit ws_size as diagnostic (deterministic per machine)
__global__ void k_diag(float* out, float val, int n){
  int i = blockIdx.x*256 + threadIdx.x;
  if (i < n) out[i] = (i==0) ? val : 0.f;
}

extern "C" void kernel_launch(void* const* d_in, const int* in_sizes, int n_in,
                              void* d_out, int out_size, void* d_ws, size_t ws_size,
                              hipStream_t stream){
  const float* x_in  = (const float*)d_in[0];
  const int*   ei    = (const int*)d_in[1];
  const float* ea    = (const float*)d_in[2];
  const int*   batch = (const int*)d_in[3];
  const float* ln_s  = (const float*)d_in[4];
  const float* ln_b  = (const float*)d_in[5];
  const float* W1    = (const float*)d_in[6];
  const float* b1    = (const float*)d_in[7];
  const float* W2    = (const float*)d_in[8];
  const float* b2    = (const float*)d_in[9];
  const float* root  = (const float*)d_in[10];
  const float* convb = (const float*)d_in[11];
  const float* dW    = (const float*)d_in[12];
  const float* db    = (const float*)d_in[13];
  const float* oW    = (const float*)d_in[14];
  const float* ob    = (const float*)d_in[15];
  float* out = (float*)d_out;

  char* ws = (char*)d_ws;
  size_t off = 0;
  auto alloc = [&](size_t bytes)->char*{
    char* p = ws + off; off = (off + bytes + 255) & ~(size_t)255; return p;
  };
  float* x_cur  = (float*)alloc((size_t)NN*DD*4);
  float* h      = (float*)alloc((size_t)NN*DD*4);
  unsigned short* ug  = (unsigned short*)alloc((size_t)LL*EE*HH*2);
  float* num_part = (float*)alloc((size_t)KSEG*NN*DD*4);
  float* Hs     = (float*)alloc((size_t)NN*DD*4);
  unsigned short* Sb0 = (unsigned short*)alloc((size_t)CHUNK*8192*2);
  unsigned short* Sb1 = (unsigned short*)alloc((size_t)CHUNK*8192*2);
  unsigned short* W2T = (unsigned short*)alloc((size_t)LL*8192*64*2);
  unsigned short* eab = (unsigned short*)alloc((size_t)EE*DD*2);
  unsigned short* W1T = (unsigned short*)alloc((size_t)LL*HH*DD*2);
  int* deg     = (int*)alloc((size_t)NN*4);
  int* row_ptr = (int*)alloc((size_t)(NN+1)*4);
  int* cursor  = (int*)alloc((size_t)NN*4);
  int* edge_id = (int*)alloc((size_t)EE*4);
  int* src_sorted = (int*)alloc((size_t)EE*4);
  int* cnt     = (int*)alloc((size_t)GG*4);
  float* pooled= (float*)alloc((size_t)GG*DD*4);
  size_t needed = off;
  if (ws_size < needed){
    k_diag<<<(out_size+255)/256, 256, 0, stream>>>(out, (float)ws_size, out_size);
    return;
  }

  k_pre <<<PRE0+PRE1+PRE2, 256, 0, stream>>>(x_in, ln_s, ln_b, x_cur, h, deg, cursor, cnt,
                                             pooled, ea, W1, W2, eab, W1T, W2T, ei, batch);
  k_scan<<<1, 256, 0, stream>>>(deg, row_ptr);
  k_fill<<<EE/256, 256, 0, stream>>>(ei, row_ptr, cursor, edge_id, src_sorted);
  k_mlp3<<<LL*(EE/128), 256, 0, stream>>>(eab, W1T, b1, ug);

  unsigned short* Sb[2] = {Sb0, Sb1};
  for (int l=0; l<LL; ++l){
    const unsigned short* ugl = ug + (size_t)l*EE*HH;
    const unsigned short* ks  = W2T + (size_t)l*8192*64;
    // pipeline: launch i = sbuild(chunk i) + gemm(chunk i-1)
    k_sbgm<<<SBB, 256, 0, stream>>>(ugl, h, row_ptr, edge_id, src_sorted,
                                    Sb[0], Hs, 0*CHUNK, SBB, Sb[1], ks, num_part, 0);
    for (int c=1; c<4; ++c){
      k_sbgm<<<SBB+GMB, 256, 0, stream>>>(ugl, h, row_ptr, edge_id, src_sorted,
                                          Sb[c&1], Hs, c*CHUNK, SBB,
                                          Sb[(c-1)&1], ks, num_part, (c-1)*CHUNK);
    }
    k_sbgm<<<GMB, 256, 0, stream>>>(ugl, h, row_ptr, edge_id, src_sorted,
                                    Sb[0], Hs, 0, 0, Sb[1], ks, num_part, 3*CHUNK);
    k_update_ln<<<NN/4, 256, 0, stream>>>(x_cur, num_part, h, Hs, deg, root, b2, convb,
                                          ln_s, ln_b, dW, db, batch, pooled,
                                          l, (l < LL-1) ? 1 : 0, (l == LL-1) ? 1 : 0);
  }
  k_final<<<GG, 128, 0, stream>>>(pooled, cnt, oW, ob, out);
}

// Round 13
// 597.857 us; speedup vs baseline: 1.2109x; 1.2109x over previous
//
#include <hip/hip_runtime.h>
#include <hip/hip_bf16.h>

// Problem constants (from reference)
#define NN 16384
#define EE 65536
#define DD 64
#define HH 128
#define LL 3
#define GG 512
#define OUTD 128
#define NEG 0.01f   // jax.nn.leaky_relu default slope

#define CHUNK 8192   // nodes per S chunk (S = CHUNK x 8192 bf16 = 128 MiB)
#define KSEG 8       // split-K partial buffers

// S column permutation (v4, d-split writer-natural order):
// c' bits: [12]=q, [11:9]=i, [8:3]=lane, [2:1]=j, [0]=kk
// -> u-index idx = 2*lane + kk ; d = 32*q + 4*i + j ; legacy kd = idx*64 + d.
// W2T' bakes the same permutation; gemm dots over c' linearly (layout-agnostic).

typedef __attribute__((ext_vector_type(8))) short short8;
typedef __attribute__((ext_vector_type(4))) float f32x4;

__device__ __forceinline__ float leaky(float x){ return x > 0.f ? x : NEG * x; }
__device__ __forceinline__ unsigned short f2bf(float f){
  union { float f; unsigned int u; } v; v.f = f;
  unsigned int r = v.u + 0x7fffu + ((v.u >> 16) & 1u);   // RNE
  return (unsigned short)(r >> 16);
}

#define CV_A (EE*DD)            // 4194304
#define CV_B (LL*HH*DD)         // 24576
#define CV_C (LL*64*8192)       // 1572864
#define PRE0 (NN/4)             // init_ln blocks
#define PRE1 ((CV_A+CV_B+CV_C)/256)
#define PRE2 (EE/256)

// ---------------- merged pre-kernel: init+LN0 | bf16 conversions | deg/cnt ----------------
__global__ void k_pre(const float* x_in, const float* ln_s, const float* ln_b,
                      float* x_cur, float* h, int* deg, int* cursor, int* cnt, float* pooled,
                      const float* ea, const float* W1, const float* W2,
                      unsigned short* eab, unsigned short* W1T, unsigned short* W2T,
                      const int* ei, const int* batch){
  int t = threadIdx.x;
  int b = blockIdx.x;
  if (b < PRE0){
    int i = b*256 + t;
    if (i < NN){ deg[i] = 0; cursor[i] = 0; }
    if (i < GG) cnt[i] = 0;
    if (i < GG*DD) pooled[i] = 0.f;
    int lane = t & 63, nl = t >> 6;
    int n = b*4 + nl;
    float v = x_in[(size_t)n*DD + lane];
    x_cur[(size_t)n*DD + lane] = v;
    float s = v;
    for (int m=1;m<64;m<<=1) s += __shfl_xor(s, m, 64);
    float mu = s * (1.0f/64.0f);
    float dv = v - mu;
    float q = dv*dv;
    for (int m=1;m<64;m<<=1) q += __shfl_xor(q, m, 64);
    float var = q * (1.0f/64.0f);
    float w = dv * rsqrtf(var + 1e-5f) * ln_s[lane] + ln_b[lane];
    h[(size_t)n*DD + lane] = leaky(w);
    return;
  }
  if (b < PRE0 + PRE1){
    int idx = (b - PRE0)*256 + t;
    if (idx < CV_A){
      eab[idx] = f2bf(ea[idx]);
    } else if (idx < CV_A + CV_B){
      int i = idx - CV_A;
      int l = i >> 13, r = i & 8191;
      int j = r >> 6, d = r & 63;
      W1T[i] = f2bf(W1[(size_t)l*DD*HH + d*HH + j]);   // W1T[l][j][d]
    } else {
      int i = idx - CV_A - CV_B;
      int l = i >> 19, rem = i & ((1<<19)-1);          // 64*8192 per layer
      int f = rem >> 13, c = rem & 8191;
      // v4 permutation decode
      int kk = c & 1, j = (c>>1) & 3, lane = (c>>3) & 63, ii = (c>>9) & 7, q = (c>>12) & 1;
      int idxu = 2*lane + kk;
      int d = 32*q + 4*ii + j;
      int kd = idxu*64 + d;
      W2T[i] = f2bf(W2[(size_t)l*HH*DD*DD + (size_t)kd*DD + f]);
    }
    return;
  }
  {
    int e = (b - PRE0 - PRE1)*256 + t;
    atomicAdd(&deg[ei[EE + e]], 1);          // row 1 of edge_index = dst
    if (e < NN) atomicAdd(&cnt[batch[e]], 1);
  }
}

__global__ void k_scan(const int* deg, int* row_ptr){
  __shared__ int part[256];
  int t = threadIdx.x;
  int base = t*64; int s = 0;
  for (int i=0;i<64;++i) s += deg[base+i];
  part[t] = s; __syncthreads();
  for (int off=1; off<256; off<<=1){
    int v = (t>=off)?part[t-off]:0; __syncthreads();
    part[t] += v; __syncthreads();
  }
  int run = (t==0)?0:part[t-1];
  if (t==0) row_ptr[0] = 0;
  for (int i=0;i<64;++i){ run += deg[base+i]; row_ptr[base+i+1] = run; }
}
__global__ void k_fill(const int* ei, const int* row_ptr, int* cursor,
                       int* edge_id, int* src_sorted){
  int e = blockIdx.x*256 + threadIdx.x;
  if (e < EE){
    int d = ei[EE + e];
    int pos = row_ptr[d] + atomicAdd(&cursor[d], 1);
    edge_id[pos] = e;
    src_sorted[pos] = ei[e];      // row 0 of edge_index = src
  }
}

// ---------------- edge MLP (ALL 3 layers up front): ug[l] = bf16(leaky(ea@W1[l]+b1[l])) ------
__global__ __launch_bounds__(256, 2)
void k_mlp3(const unsigned short* eab, const unsigned short* W1T, const float* b1,
            unsigned short* ug){
  __shared__ __align__(16) unsigned short a_lds[128][72];   // ea tile  [e][d]
  __shared__ __align__(16) unsigned short b_lds[128][72];   // W1T      [j][d]
  __shared__ __align__(16) unsigned short c_lds[128][136];  // out      [e][j]
  int t = threadIdx.x;
  int l  = blockIdx.x >> 9;                 // EE/128 = 512 blocks per layer
  int e0 = (blockIdx.x & 511) * 128;
  {
    int row = t >> 1, col = (t & 1) * 32;
    const float4* sa = (const float4*)(eab + (size_t)(e0 + row)*DD + col);
    const float4* sb = (const float4*)(W1T + (size_t)l*HH*DD + (size_t)row*DD + col);
    #pragma unroll
    for (int i=0;i<4;++i){
      *(float4*)&a_lds[row][col + 8*i] = sa[i];
      *(float4*)&b_lds[row][col + 8*i] = sb[i];
    }
  }
  __syncthreads();
  int wave = t >> 6, lane = t & 63;
  int m0 = (wave >> 1) * 64, j0 = (wave & 1) * 64;
  int lr = lane & 15, lq = lane >> 4;
  f32x4 acc[4][4];
  #pragma unroll
  for (int a=0;a<4;++a)
    #pragma unroll
    for (int b=0;b<4;++b) acc[a][b] = (f32x4){0.f,0.f,0.f,0.f};
  #pragma unroll
  for (int ks=0; ks<2; ++ks){
    short8 av[4];
    #pragma unroll
    for (int mt=0; mt<4; ++mt) av[mt] = *(const short8*)&a_lds[m0 + mt*16 + lr][ks*32 + lq*8];
    #pragma unroll
    for (int jt=0; jt<4; ++jt){
      short8 bv = *(const short8*)&b_lds[j0 + jt*16 + lr][ks*32 + lq*8];
      #pragma unroll
      for (int mt=0; mt<4; ++mt)
        acc[mt][jt] = __builtin_amdgcn_mfma_f32_16x16x32_bf16(av[mt], bv, acc[mt][jt], 0, 0, 0);
    }
  }
  // C/D: col = lane&15, row = (lane>>4)*4 + r
  #pragma unroll
  for (int mt=0; mt<4; ++mt)
    #pragma unroll
    for (int jt=0; jt<4; ++jt){
      int col = j0 + jt*16 + lr;
      float bj = b1[l*HH + col];
      #pragma unroll
      for (int r=0; r<4; ++r){
        int row = m0 + mt*16 + lq*4 + r;
        c_lds[row][col] = f2bf(leaky(acc[mt][jt][r] + bj));
      }
    }
  __syncthreads();
  {
    int row = t >> 1, half = t & 1;
    float4* dst = (float4*)(ug + (size_t)l*EE*HH + (size_t)(e0 + row)*HH + half*64);
    #pragma unroll
    for (int i=0;i<8;++i) dst[i] = *(const float4*)&c_lds[row][half*64 + 8*i];
  }
}

// ---------------- S-build v4: d-split, 2 waves/node, 64 acc regs -> 4 waves/SIMD -------------
__global__ __launch_bounds__(256, 4)
void k_sbuild4(const unsigned short* ug, const float* h, const int* row_ptr,
               const int* edge_id, const int* src_sorted,
               unsigned short* S, float* Hs, int chunk_base){
  int t = threadIdx.x, wave = t >> 6, lane = t & 63;
  int q = wave & 1;
  int nloc = blockIdx.x*2 + (wave >> 1);
  int n = chunk_base + nloc;
  int r0 = row_ptr[n], r1 = row_ptr[n+1];
  int dbase = 32*q;
  int lhalf = lane & 31;
  const unsigned int* ugd = (const unsigned int*)ug;
  float acc[64];                            // acc[dd*2+kk]
  #pragma unroll
  for (int i=0;i<64;++i) acc[i] = 0.f;
  float hs = 0.f;
  int pos = r0;
  for (; pos + 4 <= r1; pos += 4){          // two (a,b) pairs per iter
    int ea0 = edge_id[pos],    eb0 = edge_id[pos+1];
    int ea1 = edge_id[pos+2],  eb1 = edge_id[pos+3];
    int sa0 = src_sorted[pos],   sb0 = src_sorted[pos+1];
    int sa1 = src_sorted[pos+2], sb1 = src_sorted[pos+3];
    int sel0 = (lane < 32) ? sa0 : sb0;
    int sel1 = (lane < 32) ? sa1 : sb1;
    float hv0 = h[(size_t)sel0*DD + dbase + lhalf];
    float hv1 = h[(size_t)sel1*DD + dbase + lhalf];
    unsigned int ua0 = ugd[(size_t)ea0*64 + lane];
    unsigned int ub0 = ugd[(size_t)eb0*64 + lane];
    unsigned int ua1 = ugd[(size_t)ea1*64 + lane];
    unsigned int ub1 = ugd[(size_t)eb1*64 + lane];
    hs += hv0 + hv1;
    int h0 = __float_as_int(hv0), h1 = __float_as_int(hv1);
    float ua0l = __uint_as_float(ua0 << 16), ua0h = __uint_as_float(ua0 & 0xFFFF0000u);
    float ub0l = __uint_as_float(ub0 << 16), ub0h = __uint_as_float(ub0 & 0xFFFF0000u);
    float ua1l = __uint_as_float(ua1 << 16), ua1h = __uint_as_float(ua1 & 0xFFFF0000u);
    float ub1l = __uint_as_float(ub1 << 16), ub1h = __uint_as_float(ub1 & 0xFFFF0000u);
    #pragma unroll
    for (int dd=0; dd<32; ++dd){
      float sa_ = __int_as_float(__builtin_amdgcn_readlane(h0, dd));
      float sb_ = __int_as_float(__builtin_amdgcn_readlane(h0, 32+dd));
      float sa2 = __int_as_float(__builtin_amdgcn_readlane(h1, dd));
      float sb2 = __int_as_float(__builtin_amdgcn_readlane(h1, 32+dd));
      acc[dd*2+0] += ua0l*sa_; acc[dd*2+1] += ua0h*sa_;
      acc[dd*2+0] += ub0l*sb_; acc[dd*2+1] += ub0h*sb_;
      acc[dd*2+0] += ua1l*sa2; acc[dd*2+1] += ua1h*sa2;
      acc[dd*2+0] += ub1l*sb2; acc[dd*2+1] += ub1h*sb2;
    }
  }
  for (; pos + 2 <= r1; pos += 2){          // one (a,b) pair
    int ea = edge_id[pos],  eb = edge_id[pos+1];
    int sa = src_sorted[pos], sb = src_sorted[pos+1];
    int sel = (lane < 32) ? sa : sb;
    float hv = h[(size_t)sel*DD + dbase + lhalf];
    unsigned int ua = ugd[(size_t)ea*64 + lane];
    unsigned int ub = ugd[(size_t)eb*64 + lane];
    hs += hv;
    int h0 = __float_as_int(hv);
    float ual = __uint_as_float(ua << 16), uah = __uint_as_float(ua & 0xFFFF0000u);
    float ubl = __uint_as_float(ub << 16), ubh = __uint_as_float(ub & 0xFFFF0000u);
    #pragma unroll
    for (int dd=0; dd<32; ++dd){
      float sa_ = __int_as_float(__builtin_amdgcn_readlane(h0, dd));
      float sb_ = __int_as_float(__builtin_amdgcn_readlane(h0, 32+dd));
      acc[dd*2+0] += ual*sa_; acc[dd*2+1] += uah*sa_;
      acc[dd*2+0] += ubl*sb_; acc[dd*2+1] += ubh*sb_;
    }
  }
  if (pos < r1){                            // single remainder edge
    int e = edge_id[pos], s = src_sorted[pos];
    float hv = h[(size_t)s*DD + dbase + lhalf];   // lanes>=32 duplicate lanes 0-31
    unsigned int ua = ugd[(size_t)e*64 + lane];
    hs += (lane < 32) ? hv : 0.f;
    int h0 = __float_as_int(hv);
    float ual = __uint_as_float(ua << 16), uah = __uint_as_float(ua & 0xFFFF0000u);
    #pragma unroll
    for (int dd=0; dd<32; ++dd){
      float sa_ = __int_as_float(__builtin_amdgcn_readlane(h0, dd));
      acc[dd*2+0] += ual*sa_; acc[dd*2+1] += uah*sa_;
    }
  }
  // coalesced permuted stores: wave q writes chunk indices (q*8+i)*64 + lane
  float4* Srow4 = (float4*)(S + (size_t)nloc*8192);
  #pragma unroll
  for (int i=0;i<8;++i){
    union { unsigned int u[4]; float4 v; } b;
    #pragma unroll
    for (int j=0;j<4;++j){
      int dd = 4*i + j;
      b.u[j] = (unsigned int)f2bf(acc[dd*2+0]) | ((unsigned int)f2bf(acc[dd*2+1]) << 16);
    }
    Srow4[(q*8 + i)*64 + lane] = b.v;
  }
  float hs2 = hs + __shfl_xor(hs, 32, 64);
  if (lane < 32) Hs[(size_t)n*DD + dbase + lane] = hs2;
}

// ---------------- GEMM: num_part[kseg][rows,64] = S'[CHUNK,8192] @ W2T'^T (bf16 MFMA) --------
// M=128, BK=128; grid (CHUNK/128, KSEG) = 512 blocks -> 2 blocks/CU (52 KB LDS).
__global__ __launch_bounds__(256, 2)
void k_gemm(const unsigned short* S, const unsigned short* W2T,
            float* num_part, int chunk_base){
  __shared__ __align__(16) unsigned short a_lds[128][136];  // +8 pad: conflict-free b128
  __shared__ __align__(16) unsigned short b_lds[64][136];
  int t = threadIdx.x;
  int wave = t >> 6, lane = t & 63;
  int rowblk = blockIdx.x, kseg = blockIdx.y;
  int lr = lane & 15, lq = lane >> 4;
  f32x4 acc[2][4];
  #pragma unroll
  for (int a=0;a<2;++a)
    #pragma unroll
    for (int b=0;b<4;++b) acc[a][b] = (f32x4){0.f,0.f,0.f,0.f};
  int m0 = wave * 32;
  int ra = t >> 1, qa = t & 1;        // A: 128 rows x (2 x 64-col halves)
  int rb = t >> 2, qb = t & 3;        // B: 64 rows x (4 x 32-col quarters)
  for (int it = 0; it < 8; ++it){     // 8 x 128 = 1024 kd per kseg
    int kbase = kseg*1024 + it*128;
    {
      const float4* sa = (const float4*)(S + (size_t)(rowblk*128 + ra)*8192 + kbase + qa*64);
      float4* da = (float4*)&a_lds[ra][qa*64];
      #pragma unroll
      for (int i=0;i<8;++i) da[i] = sa[i];
      const float4* sb = (const float4*)(W2T + (size_t)rb*8192 + kbase + qb*32);
      float4* db = (float4*)&b_lds[rb][qb*32];
      #pragma unroll
      for (int i=0;i<4;++i) db[i] = sb[i];
    }
    __syncthreads();
    #pragma unroll
    for (int kk=0; kk<128; kk+=32){
      short8 a0 = *(const short8*)&a_lds[m0 + lr][kk + lq*8];
      short8 a1 = *(const short8*)&a_lds[m0 + 16 + lr][kk + lq*8];
      #pragma unroll
      for (int ft=0; ft<4; ++ft){
        short8 bv = *(const short8*)&b_lds[ft*16 + lr][kk + lq*8];
        acc[0][ft] = __builtin_amdgcn_mfma_f32_16x16x32_bf16(a0, bv, acc[0][ft], 0, 0, 0);
        acc[1][ft] = __builtin_amdgcn_mfma_f32_16x16x32_bf16(a1, bv, acc[1][ft], 0, 0, 0);
      }
    }
    __syncthreads();
  }
  // C/D layout: col = lane&15, row = (lane>>4)*4 + reg
  float* dstp = num_part + (size_t)kseg*NN*DD;
  #pragma unroll
  for (int rt=0; rt<2; ++rt)
    #pragma unroll
    for (int ft=0; ft<4; ++ft)
      #pragma unroll
      for (int rr=0; rr<4; ++rr){
        int m = m0 + rt*16 + lq*4 + rr;
        int f = ft*16 + lr;
        int n = chunk_base + rowblk*128 + m;
        dstp[(size_t)n*DD + f] = acc[rt][ft][rr];
      }
}

// ---------------- node update (+ fused next-layer LN), 16 nodes/block ----------------
// Staging of rl/b2l (32 KB) amortized over 16 nodes (was 4 -> 128 MB redundant traffic).
__global__ void k_update_ln(float* x, const float* num_part, float* h, const float* Hs,
                            const int* deg, const float* root, const float* b2,
                            const float* conv_b, const float* ln_s, const float* ln_b,
                            int l, int do_ln){
  __shared__ float rl[64][64];
  __shared__ float b2l[64][64];
  __shared__ float hrow[4][64];
  __shared__ float hsrow[4][64];
  int t = threadIdx.x;
  int f = t & 63, nl = t >> 6;
  for (int idx=t; idx<4096; idx+=256){
    rl[idx>>6][idx&63]  = root[(size_t)l*4096 + idx];
    b2l[idx>>6][idx&63] = b2[(size_t)l*4096 + idx];
  }
  int nbase = blockIdx.x*16;
  float cb = conv_b[l*DD + f];
  for (int i=0;i<4;++i){
    int n = nbase + i*4 + nl;
    __syncthreads();              // covers staging (i=0) and prev-iter reads
    hrow[nl][f]  = h[(size_t)n*DD + f];
    hsrow[nl][f] = Hs[(size_t)n*DD + f];
    __syncthreads();
    float dg = (float)deg[n]; if (dg < 1.f) dg = 1.f;
    float nsum = 0.f;
    #pragma unroll
    for (int p=0; p<KSEG; ++p) nsum += num_part[(size_t)p*NN*DD + (size_t)n*DD + f];
    float acc = x[(size_t)n*DD + f] + nsum/dg + cb;
    #pragma unroll
    for (int d=0; d<64; ++d)
      acc += hrow[nl][d]*rl[d][f] + hsrow[nl][d]*b2l[d][f];
    x[(size_t)n*DD + f] = acc;
    if (do_ln){
      int lp = l + 1;
      float s = acc;
      for (int m=1;m<64;m<<=1) s += __shfl_xor(s, m, 64);
      float mu = s * (1.0f/64.0f);
      float dv = acc - mu;
      float qv = dv*dv;
      for (int m=1;m<64;m<<=1) qv += __shfl_xor(qv, m, 64);
      float var = qv * (1.0f/64.0f);
      float w = dv * rsqrtf(var + 1e-5f) * ln_s[lp*DD + f] + ln_b[lp*DD + f];
      h[(size_t)n*DD + f] = leaky(w);
    }
  }
}

// ---------------- head: dense + pooled atomic accumulate, 16 nodes/block ----------------
__global__ void k_dense_pool(const float* x, const float* dW, const float* db,
                             const int* batch, float* pooled){
  __shared__ float wl[64][64];
  __shared__ float xrow[4][64];
  int t = threadIdx.x;
  int f = t & 63, nl = t >> 6;
  for (int idx=t; idx<4096; idx+=256) wl[idx>>6][idx&63] = dW[idx];
  int nbase = blockIdx.x*16;
  float dbf = db[f];
  for (int i=0;i<4;++i){
    int n = nbase + i*4 + nl;
    __syncthreads();
    xrow[nl][f] = x[(size_t)n*DD + f];
    __syncthreads();
    float acc = dbf;
    #pragma unroll
    for (int d=0; d<64; ++d) acc += xrow[nl][d]*wl[d][f];
    atomicAdd(&pooled[(size_t)batch[n]*DD + f], acc);
  }
}

__global__ void k_final(const float* pooled, const int* cnt, const float* oW,
                        const float* ob, float* out){
  __shared__ float p[64];
  int g = blockIdx.x, t = threadIdx.x;
  if (t < 64){
    float c = (float)cnt[g]; if (c < 1.f) c = 1.f;
    p[t] = leaky(pooled[(size_t)g*DD + t] / c);
  }
  __syncthreads();
  float acc = ob[t];
  #pragma unroll
  for (int f=0; f<64; ++f) acc += p[f]*oW[(size_t)f*OUTD + t];
  out[(size_t)g*OUTD + t] = acc;
}

// ws too small -> emit ws_size as diagnostic (deterministic per machine)
__global__ void k_diag(float* out, float val, int n){
  int i = blockIdx.x*256 + threadIdx.x;
  if (i < n) out[i] = (i==0) ? val : 0.f;
}

extern "C" void kernel_launch(void* const* d_in, const int* in_sizes, int n_in,
                              void* d_out, int out_size, void* d_ws, size_t ws_size,
                              hipStream_t stream){
  const float* x_in  = (const float*)d_in[0];
  const int*   ei    = (const int*)d_in[1];
  const float* ea    = (const float*)d_in[2];
  const int*   batch = (const int*)d_in[3];
  const float* ln_s  = (const float*)d_in[4];
  const float* ln_b  = (const float*)d_in[5];
  const float* W1    = (const float*)d_in[6];
  const float* b1    = (const float*)d_in[7];
  const float* W2    = (const float*)d_in[8];
  const float* b2    = (const float*)d_in[9];
  const float* root  = (const float*)d_in[10];
  const float* convb = (const float*)d_in[11];
  const float* dW    = (const float*)d_in[12];
  const float* db    = (const float*)d_in[13];
  const float* oW    = (const float*)d_in[14];
  const float* ob    = (const float*)d_in[15];
  float* out = (float*)d_out;

  char* ws = (char*)d_ws;
  size_t off = 0;
  auto alloc = [&](size_t bytes)->char*{
    char* p = ws + off; off = (off + bytes + 255) & ~(size_t)255; return p;
  };
  float* x_cur  = (float*)alloc((size_t)NN*DD*4);
  float* h      = (float*)alloc((size_t)NN*DD*4);
  unsigned short* ug  = (unsigned short*)alloc((size_t)LL*EE*HH*2);
  float* num_part = (float*)alloc((size_t)KSEG*NN*DD*4);
  float* Hs     = (float*)alloc((size_t)NN*DD*4);
  unsigned short* S   = (unsigned short*)alloc((size_t)CHUNK*8192*2);
  unsigned short* W2T = (unsigned short*)alloc((size_t)LL*8192*64*2);
  unsigned short* eab = (unsigned short*)alloc((size_t)EE*DD*2);
  unsigned short* W1T = (unsigned short*)alloc((size_t)LL*HH*DD*2);
  int* deg     = (int*)alloc((size_t)NN*4);
  int* row_ptr = (int*)alloc((size_t)(NN+1)*4);
  int* cursor  = (int*)alloc((size_t)NN*4);
  int* edge_id = (int*)alloc((size_t)EE*4);
  int* src_sorted = (int*)alloc((size_t)EE*4);
  int* cnt     = (int*)alloc((size_t)GG*4);
  float* pooled= (float*)alloc((size_t)GG*DD*4);
  size_t needed = off;
  if (ws_size < needed){
    k_diag<<<(out_size+255)/256, 256, 0, stream>>>(out, (float)ws_size, out_size);
    return;
  }

  k_pre <<<PRE0+PRE1+PRE2, 256, 0, stream>>>(x_in, ln_s, ln_b, x_cur, h, deg, cursor, cnt,
                                             pooled, ea, W1, W2, eab, W1T, W2T, ei, batch);
  k_scan<<<1, 256, 0, stream>>>(deg, row_ptr);
  k_fill<<<EE/256, 256, 0, stream>>>(ei, row_ptr, cursor, edge_id, src_sorted);
  k_mlp3<<<LL*(EE/128), 256, 0, stream>>>(eab, W1T, b1, ug);

  for (int l=0; l<LL; ++l){
    const unsigned short* ugl = ug + (size_t)l*EE*HH;
    for (int c=0; c<NN/CHUNK; ++c){
      k_sbuild4<<<CHUNK/2, 256, 0, stream>>>(ugl, h, row_ptr, edge_id, src_sorted, S, Hs, c*CHUNK);
      k_gemm   <<<dim3(CHUNK/128, KSEG), 256, 0, stream>>>(S, W2T + (size_t)l*8192*64, num_part, c*CHUNK);
    }
    k_update_ln<<<NN/16, 256, 0, stream>>>(x_cur, num_part, h, Hs, deg, root, b2, convb,
                                           ln_s, ln_b, l, (l < LL-1) ? 1 : 0);
  }
  k_dense_pool<<<NN/16, 256, 0, stream>>>(x_cur, dW, db, batch, pooled);
  k_final     <<<GG, 128, 0, stream>>>(pooled, cnt, oW, ob, out);
}

// Round 14
// 590.504 us; speedup vs baseline: 1.2260x; 1.0125x over previous
//
#include <hip/hip_runtime.h>
#include <hip/hip_bf16.h>

// Problem constants (from reference)
#define NN 16384
#define EE 65536
#define DD 64
#define HH 128
#define LL 3
#define GG 512
#define OUTD 128
#define NEG 0.01f   // jax.nn.leaky_relu default slope

#define CHUNK 8192   // nodes per S chunk (S = CHUNK x 8192 bf16 = 128 MiB)
#define KSEG 8       // split-K partial buffers

// S column permutation (v4, d-split writer-natural order):
// c' bits: [12]=q, [11:9]=i, [8:3]=lane, [2:1]=j, [0]=kk
// -> u-index idx = 2*lane + kk ; d = 32*q + 4*i + j ; legacy kd = idx*64 + d.
// W2T' bakes the same permutation; gemm dots over c' linearly (layout-agnostic).
// ug is stored in CSR(pos)-sorted edge order (mlp3 gathers its input instead),
// so sbuild streams ug linearly with no indirection.

typedef __attribute__((ext_vector_type(8))) short short8;
typedef __attribute__((ext_vector_type(4))) float f32x4;

__device__ __forceinline__ float leaky(float x){ return x > 0.f ? x : NEG * x; }
__device__ __forceinline__ unsigned short f2bf(float f){
  union { float f; unsigned int u; } v; v.f = f;
  unsigned int r = v.u + 0x7fffu + ((v.u >> 16) & 1u);   // RNE
  return (unsigned short)(r >> 16);
}

#define CV_A (EE*DD)            // 4194304
#define CV_B (LL*HH*DD)         // 24576
#define CV_C (LL*64*8192)       // 1572864
#define PRE0 (NN/4)             // init_ln blocks
#define PRE1 ((CV_A+CV_B+CV_C)/256)
#define PRE2 (EE/256)

// ---------------- merged pre-kernel: init+LN0 | bf16 conversions | deg/cnt ----------------
__global__ void k_pre(const float* x_in, const float* ln_s, const float* ln_b,
                      float* x_cur, float* h, int* deg, int* cursor, int* cnt, float* pooled,
                      const float* ea, const float* W1, const float* W2,
                      unsigned short* eab, unsigned short* W1T, unsigned short* W2T,
                      const int* ei, const int* batch){
  int t = threadIdx.x;
  int b = blockIdx.x;
  if (b < PRE0){
    int i = b*256 + t;
    if (i < NN){ deg[i] = 0; cursor[i] = 0; }
    if (i < GG) cnt[i] = 0;
    if (i < GG*DD) pooled[i] = 0.f;
    int lane = t & 63, nl = t >> 6;
    int n = b*4 + nl;
    float v = x_in[(size_t)n*DD + lane];
    x_cur[(size_t)n*DD + lane] = v;
    float s = v;
    for (int m=1;m<64;m<<=1) s += __shfl_xor(s, m, 64);
    float mu = s * (1.0f/64.0f);
    float dv = v - mu;
    float q = dv*dv;
    for (int m=1;m<64;m<<=1) q += __shfl_xor(q, m, 64);
    float var = q * (1.0f/64.0f);
    float w = dv * rsqrtf(var + 1e-5f) * ln_s[lane] + ln_b[lane];
    h[(size_t)n*DD + lane] = leaky(w);
    return;
  }
  if (b < PRE0 + PRE1){
    int idx = (b - PRE0)*256 + t;
    if (idx < CV_A){
      eab[idx] = f2bf(ea[idx]);
    } else if (idx < CV_A + CV_B){
      int i = idx - CV_A;
      int l = i >> 13, r = i & 8191;
      int j = r >> 6, d = r & 63;
      W1T[i] = f2bf(W1[(size_t)l*DD*HH + d*HH + j]);   // W1T[l][j][d]
    } else {
      int i = idx - CV_A - CV_B;
      int l = i >> 19, rem = i & ((1<<19)-1);          // 64*8192 per layer
      int f = rem >> 13, c = rem & 8191;
      // v4 permutation decode
      int kk = c & 1, j = (c>>1) & 3, lane = (c>>3) & 63, ii = (c>>9) & 7, q = (c>>12) & 1;
      int idxu = 2*lane + kk;
      int d = 32*q + 4*ii + j;
      int kd = idxu*64 + d;
      W2T[i] = f2bf(W2[(size_t)l*HH*DD*DD + (size_t)kd*DD + f]);
    }
    return;
  }
  {
    int e = (b - PRE0 - PRE1)*256 + t;
    atomicAdd(&deg[ei[EE + e]], 1);          // row 1 of edge_index = dst
    if (e < NN) atomicAdd(&cnt[batch[e]], 1);
  }
}

__global__ void k_scan(const int* deg, int* row_ptr){
  __shared__ int part[256];
  int t = threadIdx.x;
  int base = t*64; int s = 0;
  for (int i=0;i<64;++i) s += deg[base+i];
  part[t] = s; __syncthreads();
  for (int off=1; off<256; off<<=1){
    int v = (t>=off)?part[t-off]:0; __syncthreads();
    part[t] += v; __syncthreads();
  }
  int run = (t==0)?0:part[t-1];
  if (t==0) row_ptr[0] = 0;
  for (int i=0;i<64;++i){ run += deg[base+i]; row_ptr[base+i+1] = run; }
}
__global__ void k_fill(const int* ei, const int* row_ptr, int* cursor,
                       int* edge_id, int* src_sorted){
  int e = blockIdx.x*256 + threadIdx.x;
  if (e < EE){
    int d = ei[EE + e];
    int pos = row_ptr[d] + atomicAdd(&cursor[d], 1);
    edge_id[pos] = e;
    src_sorted[pos] = ei[e];      // row 0 of edge_index = src
  }
}

// ---------------- edge MLP (ALL 3 layers, CSR-sorted order): ug[l][pos] ----------------------
// Input tile gathered via edge_id (eab is 8 MB, L2-resident); output written pos-sorted
// and fully coalesced -> sbuild streams ug with zero indirection.
__global__ __launch_bounds__(256, 2)
void k_mlp3(const unsigned short* eab, const unsigned short* W1T, const float* b1,
            const int* edge_id, unsigned short* ug){
  __shared__ __align__(16) unsigned short a_lds[128][72];   // ea tile  [pos][d]
  __shared__ __align__(16) unsigned short b_lds[128][72];   // W1T      [j][d]
  __shared__ __align__(16) unsigned short c_lds[128][136];  // out      [pos][j]
  int t = threadIdx.x;
  int l  = blockIdx.x >> 9;                 // EE/128 = 512 blocks per layer
  int e0 = (blockIdx.x & 511) * 128;
  {
    int row = t >> 1, col = (t & 1) * 32;
    int eid = edge_id[e0 + row];
    const float4* sa = (const float4*)(eab + (size_t)eid*DD + col);
    const float4* sb = (const float4*)(W1T + (size_t)l*HH*DD + (size_t)row*DD + col);
    #pragma unroll
    for (int i=0;i<4;++i){
      *(float4*)&a_lds[row][col + 8*i] = sa[i];
      *(float4*)&b_lds[row][col + 8*i] = sb[i];
    }
  }
  __syncthreads();
  int wave = t >> 6, lane = t & 63;
  int m0 = (wave >> 1) * 64, j0 = (wave & 1) * 64;
  int lr = lane & 15, lq = lane >> 4;
  f32x4 acc[4][4];
  #pragma unroll
  for (int a=0;a<4;++a)
    #pragma unroll
    for (int b=0;b<4;++b) acc[a][b] = (f32x4){0.f,0.f,0.f,0.f};
  #pragma unroll
  for (int ks=0; ks<2; ++ks){
    short8 av[4];
    #pragma unroll
    for (int mt=0; mt<4; ++mt) av[mt] = *(const short8*)&a_lds[m0 + mt*16 + lr][ks*32 + lq*8];
    #pragma unroll
    for (int jt=0; jt<4; ++jt){
      short8 bv = *(const short8*)&b_lds[j0 + jt*16 + lr][ks*32 + lq*8];
      #pragma unroll
      for (int mt=0; mt<4; ++mt)
        acc[mt][jt] = __builtin_amdgcn_mfma_f32_16x16x32_bf16(av[mt], bv, acc[mt][jt], 0, 0, 0);
    }
  }
  // C/D: col = lane&15, row = (lane>>4)*4 + r
  #pragma unroll
  for (int mt=0; mt<4; ++mt)
    #pragma unroll
    for (int jt=0; jt<4; ++jt){
      int col = j0 + jt*16 + lr;
      float bj = b1[l*HH + col];
      #pragma unroll
      for (int r=0; r<4; ++r){
        int row = m0 + mt*16 + lq*4 + r;
        c_lds[row][col] = f2bf(leaky(acc[mt][jt][r] + bj));
      }
    }
  __syncthreads();
  {
    int row = t >> 1, half = t & 1;
    float4* dst = (float4*)(ug + (size_t)l*EE*HH + (size_t)(e0 + row)*HH + half*64);
    #pragma unroll
    for (int i=0;i<8;++i) dst[i] = *(const float4*)&c_lds[row][half*64 + 8*i];
  }
}

// ---------------- S-build v5: d-split, 2 waves/node; ug streamed linearly (pos order) --------
__global__ __launch_bounds__(256, 4)
void k_sbuild5(const unsigned short* ug, const float* h, const int* row_ptr,
               const int* src_sorted,
               unsigned short* S, float* Hs, int chunk_base){
  int t = threadIdx.x, wave = t >> 6, lane = t & 63;
  int q = wave & 1;
  int nloc = blockIdx.x*2 + (wave >> 1);
  int n = chunk_base + nloc;
  int r0 = row_ptr[n], r1 = row_ptr[n+1];
  int dbase = 32*q;
  int lhalf = lane & 31;
  const unsigned int* ugd = (const unsigned int*)ug;
  float acc[64];                            // acc[dd*2+kk]
  #pragma unroll
  for (int i=0;i<64;++i) acc[i] = 0.f;
  float hs = 0.f;
  int pos = r0;
  for (; pos + 4 <= r1; pos += 4){          // two (a,b) pairs per iter
    int sa0 = src_sorted[pos],   sb0 = src_sorted[pos+1];
    int sa1 = src_sorted[pos+2], sb1 = src_sorted[pos+3];
    int sel0 = (lane < 32) ? sa0 : sb0;
    int sel1 = (lane < 32) ? sa1 : sb1;
    float hv0 = h[(size_t)sel0*DD + dbase + lhalf];
    float hv1 = h[(size_t)sel1*DD + dbase + lhalf];
    unsigned int ua0 = ugd[(size_t)(pos+0)*64 + lane];
    unsigned int ub0 = ugd[(size_t)(pos+1)*64 + lane];
    unsigned int ua1 = ugd[(size_t)(pos+2)*64 + lane];
    unsigned int ub1 = ugd[(size_t)(pos+3)*64 + lane];
    hs += hv0 + hv1;
    int h0 = __float_as_int(hv0), h1 = __float_as_int(hv1);
    float ua0l = __uint_as_float(ua0 << 16), ua0h = __uint_as_float(ua0 & 0xFFFF0000u);
    float ub0l = __uint_as_float(ub0 << 16), ub0h = __uint_as_float(ub0 & 0xFFFF0000u);
    float ua1l = __uint_as_float(ua1 << 16), ua1h = __uint_as_float(ua1 & 0xFFFF0000u);
    float ub1l = __uint_as_float(ub1 << 16), ub1h = __uint_as_float(ub1 & 0xFFFF0000u);
    #pragma unroll
    for (int dd=0; dd<32; ++dd){
      float sa_ = __int_as_float(__builtin_amdgcn_readlane(h0, dd));
      float sb_ = __int_as_float(__builtin_amdgcn_readlane(h0, 32+dd));
      float sa2 = __int_as_float(__builtin_amdgcn_readlane(h1, dd));
      float sb2 = __int_as_float(__builtin_amdgcn_readlane(h1, 32+dd));
      acc[dd*2+0] += ua0l*sa_; acc[dd*2+1] += ua0h*sa_;
      acc[dd*2+0] += ub0l*sb_; acc[dd*2+1] += ub0h*sb_;
      acc[dd*2+0] += ua1l*sa2; acc[dd*2+1] += ua1h*sa2;
      acc[dd*2+0] += ub1l*sb2; acc[dd*2+1] += ub1h*sb2;
    }
  }
  for (; pos + 2 <= r1; pos += 2){          // one (a,b) pair
    int sa = src_sorted[pos], sb = src_sorted[pos+1];
    int sel = (lane < 32) ? sa : sb;
    float hv = h[(size_t)sel*DD + dbase + lhalf];
    unsigned int ua = ugd[(size_t)(pos+0)*64 + lane];
    unsigned int ub = ugd[(size_t)(pos+1)*64 + lane];
    hs += hv;
    int h0 = __float_as_int(hv);
    float ual = __uint_as_float(ua << 16), uah = __uint_as_float(ua & 0xFFFF0000u);
    float ubl = __uint_as_float(ub << 16), ubh = __uint_as_float(ub & 0xFFFF0000u);
    #pragma unroll
    for (int dd=0; dd<32; ++dd){
      float sa_ = __int_as_float(__builtin_amdgcn_readlane(h0, dd));
      float sb_ = __int_as_float(__builtin_amdgcn_readlane(h0, 32+dd));
      acc[dd*2+0] += ual*sa_; acc[dd*2+1] += uah*sa_;
      acc[dd*2+0] += ubl*sb_; acc[dd*2+1] += ubh*sb_;
    }
  }
  if (pos < r1){                            // single remainder edge
    int s = src_sorted[pos];
    float hv = h[(size_t)s*DD + dbase + lhalf];   // lanes>=32 duplicate lanes 0-31
    unsigned int ua = ugd[(size_t)pos*64 + lane];
    hs += (lane < 32) ? hv : 0.f;
    int h0 = __float_as_int(hv);
    float ual = __uint_as_float(ua << 16), uah = __uint_as_float(ua & 0xFFFF0000u);
    #pragma unroll
    for (int dd=0; dd<32; ++dd){
      float sa_ = __int_as_float(__builtin_amdgcn_readlane(h0, dd));
      acc[dd*2+0] += ual*sa_; acc[dd*2+1] += uah*sa_;
    }
  }
  // coalesced permuted stores: wave q writes chunk indices (q*8+i)*64 + lane
  float4* Srow4 = (float4*)(S + (size_t)nloc*8192);
  #pragma unroll
  for (int i=0;i<8;++i){
    union { unsigned int u[4]; float4 v; } b;
    #pragma unroll
    for (int j=0;j<4;++j){
      int dd = 4*i + j;
      b.u[j] = (unsigned int)f2bf(acc[dd*2+0]) | ((unsigned int)f2bf(acc[dd*2+1]) << 16);
    }
    Srow4[(q*8 + i)*64 + lane] = b.v;
  }
  float hs2 = hs + __shfl_xor(hs, 32, 64);
  if (lane < 32) Hs[(size_t)n*DD + dbase + lane] = hs2;
}

// ---------------- GEMM: num_part[kseg][rows,64] = S'[CHUNK,8192] @ W2T'^T (bf16 MFMA) --------
// M=128, BK=128; grid (CHUNK/128, KSEG) = 512 blocks -> 2 blocks/CU (52 KB LDS).
__global__ __launch_bounds__(256, 2)
void k_gemm(const unsigned short* S, const unsigned short* W2T,
            float* num_part, int chunk_base){
  __shared__ __align__(16) unsigned short a_lds[128][136];  // +8 pad: conflict-free b128
  __shared__ __align__(16) unsigned short b_lds[64][136];
  int t = threadIdx.x;
  int wave = t >> 6, lane = t & 63;
  int rowblk = blockIdx.x, kseg = blockIdx.y;
  int lr = lane & 15, lq = lane >> 4;
  f32x4 acc[2][4];
  #pragma unroll
  for (int a=0;a<2;++a)
    #pragma unroll
    for (int b=0;b<4;++b) acc[a][b] = (f32x4){0.f,0.f,0.f,0.f};
  int m0 = wave * 32;
  int ra = t >> 1, qa = t & 1;        // A: 128 rows x (2 x 64-col halves)
  int rb = t >> 2, qb = t & 3;        // B: 64 rows x (4 x 32-col quarters)
  for (int it = 0; it < 8; ++it){     // 8 x 128 = 1024 kd per kseg
    int kbase = kseg*1024 + it*128;
    {
      const float4* sa = (const float4*)(S + (size_t)(rowblk*128 + ra)*8192 + kbase + qa*64);
      float4* da = (float4*)&a_lds[ra][qa*64];
      #pragma unroll
      for (int i=0;i<8;++i) da[i] = sa[i];
      const float4* sb = (const float4*)(W2T + (size_t)rb*8192 + kbase + qb*32);
      float4* db = (float4*)&b_lds[rb][qb*32];
      #pragma unroll
      for (int i=0;i<4;++i) db[i] = sb[i];
    }
    __syncthreads();
    #pragma unroll
    for (int kk=0; kk<128; kk+=32){
      short8 a0 = *(const short8*)&a_lds[m0 + lr][kk + lq*8];
      short8 a1 = *(const short8*)&a_lds[m0 + 16 + lr][kk + lq*8];
      #pragma unroll
      for (int ft=0; ft<4; ++ft){
        short8 bv = *(const short8*)&b_lds[ft*16 + lr][kk + lq*8];
        acc[0][ft] = __builtin_amdgcn_mfma_f32_16x16x32_bf16(a0, bv, acc[0][ft], 0, 0, 0);
        acc[1][ft] = __builtin_amdgcn_mfma_f32_16x16x32_bf16(a1, bv, acc[1][ft], 0, 0, 0);
      }
    }
    __syncthreads();
  }
  // C/D layout: col = lane&15, row = (lane>>4)*4 + reg
  float* dstp = num_part + (size_t)kseg*NN*DD;
  #pragma unroll
  for (int rt=0; rt<2; ++rt)
    #pragma unroll
    for (int ft=0; ft<4; ++ft)
      #pragma unroll
      for (int rr=0; rr<4; ++rr){
        int m = m0 + rt*16 + lq*4 + rr;
        int f = ft*16 + lr;
        int n = chunk_base + rowblk*128 + m;
        dstp[(size_t)n*DD + f] = acc[rt][ft][rr];
      }
}

// ---------------- node update (+ fused next-layer LN), 16 nodes/block ----------------
__global__ void k_update_ln(float* x, const float* num_part, float* h, const float* Hs,
                            const int* deg, const float* root, const float* b2,
                            const float* conv_b, const float* ln_s, const float* ln_b,
                            int l, int do_ln){
  __shared__ float rl[64][64];
  __shared__ float b2l[64][64];
  __shared__ float hrow[4][64];
  __shared__ float hsrow[4][64];
  int t = threadIdx.x;
  int f = t & 63, nl = t >> 6;
  for (int idx=t; idx<4096; idx+=256){
    rl[idx>>6][idx&63]  = root[(size_t)l*4096 + idx];
    b2l[idx>>6][idx&63] = b2[(size_t)l*4096 + idx];
  }
  int nbase = blockIdx.x*16;
  float cb = conv_b[l*DD + f];
  for (int i=0;i<4;++i){
    int n = nbase + i*4 + nl;
    __syncthreads();              // covers staging (i=0) and prev-iter reads
    hrow[nl][f]  = h[(size_t)n*DD + f];
    hsrow[nl][f] = Hs[(size_t)n*DD + f];
    __syncthreads();
    float dg = (float)deg[n]; if (dg < 1.f) dg = 1.f;
    float nsum = 0.f;
    #pragma unroll
    for (int p=0; p<KSEG; ++p) nsum += num_part[(size_t)p*NN*DD + (size_t)n*DD + f];
    float acc = x[(size_t)n*DD + f] + nsum/dg + cb;
    #pragma unroll
    for (int d=0; d<64; ++d)
      acc += hrow[nl][d]*rl[d][f] + hsrow[nl][d]*b2l[d][f];
    x[(size_t)n*DD + f] = acc;
    if (do_ln){
      int lp = l + 1;
      float s = acc;
      for (int m=1;m<64;m<<=1) s += __shfl_xor(s, m, 64);
      float mu = s * (1.0f/64.0f);
      float dv = acc - mu;
      float qv = dv*dv;
      for (int m=1;m<64;m<<=1) qv += __shfl_xor(qv, m, 64);
      float var = qv * (1.0f/64.0f);
      float w = dv * rsqrtf(var + 1e-5f) * ln_s[lp*DD + f] + ln_b[lp*DD + f];
      h[(size_t)n*DD + f] = leaky(w);
    }
  }
}

// ---------------- head: dense + pooled atomic accumulate, 16 nodes/block ----------------
__global__ void k_dense_pool(const float* x, const float* dW, const float* db,
                             const int* batch, float* pooled){
  __shared__ float wl[64][64];
  __shared__ float xrow[4][64];
  int t = threadIdx.x;
  int f = t & 63, nl = t >> 6;
  for (int idx=t; idx<4096; idx+=256) wl[idx>>6][idx&63] = dW[idx];
  int nbase = blockIdx.x*16;
  float dbf = db[f];
  for (int i=0;i<4;++i){
    int n = nbase + i*4 + nl;
    __syncthreads();
    xrow[nl][f] = x[(size_t)n*DD + f];
    __syncthreads();
    float acc = dbf;
    #pragma unroll
    for (int d=0; d<64; ++d) acc += xrow[nl][d]*wl[d][f];
    atomicAdd(&pooled[(size_t)batch[n]*DD + f], acc);
  }
}

__global__ void k_final(const float* pooled, const int* cnt, const float* oW,
                        const float* ob, float* out){
  __shared__ float p[64];
  int g = blockIdx.x, t = threadIdx.x;
  if (t < 64){
    float c = (float)cnt[g]; if (c < 1.f) c = 1.f;
    p[t] = leaky(pooled[(size_t)g*DD + t] / c);
  }
  __syncthreads();
  float acc = ob[t];
  #pragma unroll
  for (int f=0; f<64; ++f) acc += p[f]*oW[(size_t)f*OUTD + t];
  out[(size_t)g*OUTD + t] = acc;
}

// ws too small -> emit ws_size as diagnostic (deterministic per machine)
__global__ void k_diag(float* out, float val, int n){
  int i = blockIdx.x*256 + threadIdx.x;
  if (i < n) out[i] = (i==0) ? val : 0.f;
}

extern "C" void kernel_launch(void* const* d_in, const int* in_sizes, int n_in,
                              void* d_out, int out_size, void* d_ws, size_t ws_size,
                              hipStream_t stream){
  const float* x_in  = (const float*)d_in[0];
  const int*   ei    = (const int*)d_in[1];
  const float* ea    = (const float*)d_in[2];
  const int*   batch = (const int*)d_in[3];
  const float* ln_s  = (const float*)d_in[4];
  const float* ln_b  = (const float*)d_in[5];
  const float* W1    = (const float*)d_in[6];
  const float* b1    = (const float*)d_in[7];
  const float* W2    = (const float*)d_in[8];
  const float* b2    = (const float*)d_in[9];
  const float* root  = (const float*)d_in[10];
  const float* convb = (const float*)d_in[11];
  const float* dW    = (const float*)d_in[12];
  const float* db    = (const float*)d_in[13];
  const float* oW    = (const float*)d_in[14];
  const float* ob    = (const float*)d_in[15];
  float* out = (float*)d_out;

  char* ws = (char*)d_ws;
  size_t off = 0;
  auto alloc = [&](size_t bytes)->char*{
    char* p = ws + off; off = (off + bytes + 255) & ~(size_t)255; return p;
  };
  float* x_cur  = (float*)alloc((size_t)NN*DD*4);
  float* h      = (float*)alloc((size_t)NN*DD*4);
  unsigned short* ug  = (unsigned short*)alloc((size_t)LL*EE*HH*2);
  float* num_part = (float*)alloc((size_t)KSEG*NN*DD*4);
  float* Hs     = (float*)alloc((size_t)NN*DD*4);
  unsigned short* S   = (unsigned short*)alloc((size_t)CHUNK*8192*2);
  unsigned short* W2T = (unsigned short*)alloc((size_t)LL*8192*64*2);
  unsigned short* eab = (unsigned short*)alloc((size_t)EE*DD*2);
  unsigned short* W1T = (unsigned short*)alloc((size_t)LL*HH*DD*2);
  int* deg     = (int*)alloc((size_t)NN*4);
  int* row_ptr = (int*)alloc((size_t)(NN+1)*4);
  int* cursor  = (int*)alloc((size_t)NN*4);
  int* edge_id = (int*)alloc((size_t)EE*4);
  int* src_sorted = (int*)alloc((size_t)EE*4);
  int* cnt     = (int*)alloc((size_t)GG*4);
  float* pooled= (float*)alloc((size_t)GG*DD*4);
  size_t needed = off;
  if (ws_size < needed){
    k_diag<<<(out_size+255)/256, 256, 0, stream>>>(out, (float)ws_size, out_size);
    return;
  }

  k_pre <<<PRE0+PRE1+PRE2, 256, 0, stream>>>(x_in, ln_s, ln_b, x_cur, h, deg, cursor, cnt,
                                             pooled, ea, W1, W2, eab, W1T, W2T, ei, batch);
  k_scan<<<1, 256, 0, stream>>>(deg, row_ptr);
  k_fill<<<EE/256, 256, 0, stream>>>(ei, row_ptr, cursor, edge_id, src_sorted);
  k_mlp3<<<LL*(EE/128), 256, 0, stream>>>(eab, W1T, b1, edge_id, ug);

  for (int l=0; l<LL; ++l){
    const unsigned short* ugl = ug + (size_t)l*EE*HH;
    for (int c=0; c<NN/CHUNK; ++c){
      k_sbuild5<<<CHUNK/2, 256, 0, stream>>>(ugl, h, row_ptr, src_sorted, S, Hs, c*CHUNK);
      k_gemm   <<<dim3(CHUNK/128, KSEG), 256, 0, stream>>>(S, W2T + (size_t)l*8192*64, num_part, c*CHUNK);
    }
    k_update_ln<<<NN/16, 256, 0, stream>>>(x_cur, num_part, h, Hs, deg, root, b2, convb,
                                           ln_s, ln_b, l, (l < LL-1) ? 1 : 0);
  }
  k_dense_pool<<<NN/16, 256, 0, stream>>>(x_cur, dW, db, batch, pooled);
  k_final     <<<GG, 128, 0, stream>>>(pooled, cnt, oW, ob, out);
}